// Round 12
// baseline (622.321 us; speedup 1.0000x reference)
//
#include <hip/hip_runtime.h>
#include <hip/hip_bf16.h>

#define N_NODES 50000
#define N_EDGES 1600000
#define IN_CH 64
#define NUM_HID 256
#define NUM_CLASSES 16
#define NUM_GRAPHS 512
#define NBS 196  // ceil(N_NODES/256)

typedef short bf16x8 __attribute__((ext_vector_type(8)));
typedef float f32x4 __attribute__((ext_vector_type(4)));

#if __has_builtin(__builtin_amdgcn_rcpf)
#define RCPF(x) __builtin_amdgcn_rcpf(x)
#else
#define RCPF(x) (1.0f / (x))
#endif

__device__ inline unsigned short f2b(float f) {
    unsigned int u = __float_as_uint(f);
    unsigned int r = (u + 0x7FFF + ((u >> 16) & 1)) >> 16;
    return (unsigned short)r;
}
__device__ inline float b2f(unsigned short u) {
    return __uint_as_float(((unsigned int)u) << 16);
}

// ---------------- preprocessing ----------------
__global__ void prep_w_kernel(const float* __restrict__ wf1, const float* __restrict__ ws1,
                              const float* __restrict__ wf2, const float* __restrict__ ws2,
                              unsigned short* __restrict__ wb1, unsigned short* __restrict__ wb2) {
    int i = blockIdx.x * 256 + threadIdx.x;
    if (i >= 128 * 160) return;
    int r = i / 160, k = i - r * 160;
    wb1[i] = f2b(r < 64 ? wf1[r * 160 + k] : ws1[(r - 64) * 160 + k]);
    wb2[i] = f2b(r < 64 ? wf2[r * 160 + k] : ws2[(r - 64) * 160 + k]);
}

__global__ void prep_x_kernel(const float4* __restrict__ x, unsigned short* __restrict__ xb) {
    int i = blockIdx.x * 256 + threadIdx.x;
    if (i >= N_NODES * 16) return;
    float4 v = x[i];
    ushort4 u; u.x = f2b(v.x); u.y = f2b(v.y); u.z = f2b(v.z); u.w = f2b(v.w);
    *(ushort4*)(xb + i * 4) = u;
}

__global__ void hist_kernel(const int* __restrict__ ei, int* __restrict__ cnt) {
    int i = blockIdx.x * 256 + threadIdx.x;
    if (i < N_EDGES) atomicAdd(&cnt[ei[N_EDGES + i]], 1);
}

__global__ void bsum_kernel(const int* __restrict__ cnt, int* __restrict__ bsum) {
    __shared__ int sm[256];
    int i = blockIdx.x * 256 + threadIdx.x;
    sm[threadIdx.x] = (i < N_NODES) ? cnt[i] : 0;
    __syncthreads();
    for (int off = 128; off > 0; off >>= 1) {
        if (threadIdx.x < off) sm[threadIdx.x] += sm[threadIdx.x + off];
        __syncthreads();
    }
    if (threadIdx.x == 0) bsum[blockIdx.x] = sm[0];
}

__global__ void bscan_kernel(const int* __restrict__ bsum, int* __restrict__ boffs) {
    __shared__ int sm[256];
    int t = threadIdx.x;
    int v = (t < NBS) ? bsum[t] : 0;
    sm[t] = v; __syncthreads();
    for (int off = 1; off < 256; off <<= 1) {
        int u = (t >= off) ? sm[t - off] : 0;
        __syncthreads();
        sm[t] += u;
        __syncthreads();
    }
    if (t < NBS) boffs[t] = sm[t] - v;  // exclusive
}

__global__ void apply_kernel(const int* __restrict__ cnt, const int* __restrict__ boffs,
                             int* __restrict__ cursor, float* __restrict__ invdeg) {
    __shared__ int sm[256];
    int t = threadIdx.x, i = blockIdx.x * 256 + t;
    int c = (i < N_NODES) ? cnt[i] : 0;
    sm[t] = c; __syncthreads();
    for (int off = 1; off < 256; off <<= 1) {
        int u = (t >= off) ? sm[t - off] : 0;
        __syncthreads();
        sm[t] += u;
        __syncthreads();
    }
    if (i < N_NODES) {
        cursor[i] = boffs[blockIdx.x] + sm[t] - c;
        invdeg[i] = 1.0f / fmaxf((float)c, 1.0f);
    }
}

// scatter + in-place sort of edge_attr to dst-order (bf16), fused
__global__ void scatter_kernel(const int* __restrict__ ei, int* __restrict__ cursor,
                               const float* __restrict__ ea,
                               int2* __restrict__ sed, unsigned short* __restrict__ eab) {
    int e = blockIdx.x * 256 + threadIdx.x;
    if (e >= N_EDGES) return;
    int s = ei[e], d = ei[N_EDGES + e];
    int p = atomicAdd(&cursor[d], 1);
    sed[p] = make_int2(s, d);
    const float4* src = (const float4*)(ea + (size_t)e * 32);
    unsigned short* dst = eab + (size_t)p * 32;
    #pragma unroll
    for (int j = 0; j < 8; ++j) {
        float4 v = src[j];
        ushort4 u; u.x = f2b(v.x); u.y = f2b(v.y); u.z = f2b(v.z); u.w = f2b(v.w);
        *(ushort4*)(dst + j * 4) = u;
    }
}

// ---------------- edge pass: wave = 64 edges x 16 ch (B halved to 40 VGPR) ----------------
__global__ __launch_bounds__(256, 2)
void edge_mfma(const unsigned short* __restrict__ xb,
               const int2* __restrict__ sed, const unsigned short* __restrict__ eab,
               const unsigned short* __restrict__ wb,
               const float* __restrict__ bfv, const float* __restrict__ bsv,
               float* __restrict__ agg)
{
    __shared__ __align__(16) unsigned short Zd[2][64 * 64];  // chunk c of row e holds data chunk c^(e&7)
    __shared__ __align__(16) unsigned short Zs[2][64 * 64];
    __shared__ __align__(16) unsigned short Ze[2][64 * 32];  // chunk c holds data chunk c^((e>>1)&3)
    // total LDS = 40960 B exactly -> 4 blocks/CU

    const int tid = threadIdx.x;
    const int w = tid >> 6, lane = tid & 63, lr = lane & 15, lq = lane >> 4;
    const int chw = w * 16;   // this wave's channel quarter

    // B frags: both mats, ONE ch-quarter, 5 ks: 10 x 16B = 40 VGPR
    bf16x8 B[2][5];
    #pragma unroll
    for (int mat = 0; mat < 2; ++mat)
        #pragma unroll
        for (int ks = 0; ks < 5; ++ks)
            B[mat][ks] = *(const bf16x8*)(wb + (size_t)(mat * 64 + chw + lr) * 160 + ks * 32 + lq * 8);

    const float biasF = bfv[chw + lr];
    const float biasS = bsv[chw + lr];

    const int rA0 = tid >> 3, cA0 = tid & 7;
    const int rA1 = rA0 + 32;
    const int rE = tid >> 2, cE = tid & 3;
    const int dcA0 = cA0 ^ (rA0 & 7), dcA1 = cA0 ^ (rA1 & 7);
    const int dcE8 = (cE ^ ((rE >> 1) & 3)) * 8;

    const int NT = N_EDGES / 64;
    const int nblk = gridDim.x;

    bf16x8 vd0, vs0;        // ISSUE_A regs (rows 0..31)
    bf16x8 vd1, vs1, veb;   // ISSUE_B regs (rows 32..63 + eab)

    #define ISSUE_A(T) do { \
        int e0_ = (T) * 64; \
        int2 sA0 = sed[e0_ + rA0]; \
        vd0 = *(const bf16x8*)(xb + (size_t)sA0.y * 64 + dcA0 * 8); \
        vs0 = *(const bf16x8*)(xb + (size_t)sA0.x * 64 + dcA0 * 8); \
    } while (0)
    #define ISSUE_B(T) do { \
        int e0_ = (T) * 64; \
        int2 sA1 = sed[e0_ + rA1]; \
        vd1 = *(const bf16x8*)(xb + (size_t)sA1.y * 64 + dcA1 * 8); \
        vs1 = *(const bf16x8*)(xb + (size_t)sA1.x * 64 + dcA1 * 8); \
        veb = *(const bf16x8*)(eab + (size_t)(e0_ + rE) * 32 + dcE8); \
    } while (0)
    #define WRITE_A(PAR) do { \
        *(bf16x8*)&Zd[PAR][rA0 * 64 + cA0 * 8] = vd0; \
        *(bf16x8*)&Zs[PAR][rA0 * 64 + cA0 * 8] = vs0; \
    } while (0)
    #define WRITE_B(PAR) do { \
        *(bf16x8*)&Zd[PAR][rA1 * 64 + cA0 * 8] = vd1; \
        *(bf16x8*)&Zs[PAR][rA1 * 64 + cA0 * 8] = vs1; \
        *(bf16x8*)&Ze[PAR][rE * 32 + cE * 8] = veb; \
    } while (0)
    #define SOFT_BARRIER() do { \
        asm volatile("s_waitcnt lgkmcnt(0)" ::: "memory"); \
        __builtin_amdgcn_s_barrier(); \
    } while (0)

    int t = blockIdx.x;
    if (t < NT) { ISSUE_A(t); WRITE_A(0); ISSUE_B(t); WRITE_B(0); }
    SOFT_BARRIER();
    int par = 0;

    for (; t < NT; t += nblk) {
        int tn = t + nblk;
        bool pf = tn < NT;
        int dme = sed[t * 64 + lane].y;   // current tile's dst per lane (coalesced, L2-hot)
        if (pf) ISSUE_A(tn);

        // ---- k-loop: all 64 edges x this wave's 16 ch, both mats ----
        f32x4 aF[4] = {}; f32x4 aS[4] = {};
        #pragma unroll
        for (int ks = 0; ks < 5; ++ks) {
            bf16x8 a[4];
            #pragma unroll
            for (int m = 0; m < 4; ++m) {
                const int rm = m * 16 + lr;
                if (ks < 2) {
                    int j = ks * 4 + lq;
                    a[m] = *(const bf16x8*)&Zd[par][rm * 64 + ((j ^ (rm & 7)) * 8)];
                } else if (ks < 4) {
                    int j = (ks - 2) * 4 + lq;
                    a[m] = *(const bf16x8*)&Zs[par][rm * 64 + ((j ^ (rm & 7)) * 8)];
                } else {
                    a[m] = *(const bf16x8*)&Ze[par][rm * 32 + ((lq ^ ((rm >> 1) & 3)) * 8)];
                }
            }
            #pragma unroll
            for (int m = 0; m < 4; ++m) {
                aF[m] = __builtin_amdgcn_mfma_f32_16x16x32_bf16(a[m], B[0][ks], aF[m], 0, 0, 0);
                aS[m] = __builtin_amdgcn_mfma_f32_16x16x32_bf16(a[m], B[1][ks], aS[m], 0, 0, 0);
            }
        }

        if (pf) { WRITE_A(par ^ 1); ISSUE_B(tn); }  // free A regs, issue late half

        // ---- activation in registers ----
        float val[16];   // row r = m*16 + lq*4 + i, ch = chw + lr
        #pragma unroll
        for (int m = 0; m < 4; ++m)
            #pragma unroll
            for (int i = 0; i < 4; ++i) {
                float f = aF[m][i] + biasF;
                float s = aS[m][i] + biasS;
                float sig = RCPF(1.0f + __expf(-f));
                float sp = fmaxf(s, 0.0f) + __logf(1.0f + __expf(-fabsf(s)));
                val[m * 4 + i] = sig * sp;
            }

        // ---- in-register segmented run-reduction over all 64 edges ----
        {
            int dprev = __shfl(dme, lane - 1);
            unsigned long long bmask = __ballot((lane == 0) || (dme != dprev));
            while (bmask) {
                int lo = (int)__builtin_ctzll(bmask);
                bmask &= bmask - 1;
                int hi = bmask ? (int)__builtin_ctzll(bmask) : 64;
                int dst = __shfl(dme, lo);   // wave-uniform
                float t0 = 0.0f;
                #pragma unroll
                for (int m = 0; m < 4; ++m)
                    #pragma unroll
                    for (int i = 0; i < 4; ++i) {
                        int r = m * 16 + lq * 4 + i;
                        t0 += ((r >= lo) && (r < hi)) ? val[m * 4 + i] : 0.0f;
                    }
                t0 += __shfl_xor(t0, 16);
                t0 += __shfl_xor(t0, 32);
                if (lq == 0)
                    atomicAdd(&agg[(size_t)dst * 64 + chw + lr], t0);
            }
        }

        if (pf) WRITE_B(par ^ 1);
        SOFT_BARRIER();  // lgkm only: staged LDS visible; atomics stay in flight
        par ^= 1;
    }
    #undef ISSUE_A
    #undef ISSUE_B
    #undef WRITE_A
    #undef WRITE_B
    #undef SOFT_BARRIER
}

// ---------------- residual: hb = bf16(agg*inv_deg + x) ----------------
__global__ void resid2_kernel(const float4* __restrict__ agg, const float* __restrict__ inv_deg,
                              const float4* __restrict__ x, unsigned short* __restrict__ hb)
{
    int i = blockIdx.x * 256 + threadIdx.x;
    if (i >= N_NODES * 16) return;
    int n = i >> 4;
    float iv = inv_deg[n];
    float4 a = agg[i], xv = x[i];
    ushort4 u;
    u.x = f2b(a.x * iv + xv.x); u.y = f2b(a.y * iv + xv.y);
    u.z = f2b(a.z * iv + xv.z); u.w = f2b(a.w * iv + xv.w);
    *(ushort4*)(hb + i * 4) = u;
}

// ---------------- layer-2 residual + pooling: run-reduction over SORTED batch ----------------
__global__ void pool2_kernel(const float* __restrict__ agg, const float* __restrict__ inv_deg,
                             const unsigned short* __restrict__ hb, const int* __restrict__ batch,
                             float* __restrict__ gsum, float* __restrict__ gcnt)
{
    const int ch = threadIdx.x & 63, sub = threadIdx.x >> 6;
    const int base = blockIdx.x * 64 + sub * 16;
    float acc = 0.0f;
    int gcur = -1, rl = 0;
    #pragma unroll
    for (int j = 0; j < 16; ++j) {
        int n = base + j;
        if (n >= N_NODES) break;
        int g = batch[n];
        float v = agg[(size_t)n * 64 + ch] * inv_deg[n] + b2f(hb[(size_t)n * 64 + ch]);
        if (g != gcur) {
            if (gcur >= 0) {
                atomicAdd(&gsum[gcur * 64 + ch], acc);
                if (ch == 0) atomicAdd(&gcnt[gcur], (float)rl);
            }
            gcur = g; acc = v; rl = 1;
        } else {
            acc += v; rl++;
        }
    }
    if (gcur >= 0) {
        atomicAdd(&gsum[gcur * 64 + ch], acc);
        if (ch == 0) atomicAdd(&gcnt[gcur], (float)rl);
    }
}

// ---------------- head: MLP + log_softmax ----------------
__global__ __launch_bounds__(64)
void head_kernel(const float* __restrict__ gsum, const float* __restrict__ gcnt,
                 const float* __restrict__ w1, const float* __restrict__ b1,
                 const float* __restrict__ w2, const float* __restrict__ b2,
                 float* __restrict__ out)
{
    __shared__ float gv[64];
    __shared__ float hid[256];
    __shared__ float outv[16];
    const int g = blockIdx.x, t = threadIdx.x;
    float cnt = fmaxf(gcnt[g], 1.0f);
    gv[t] = gsum[g * 64 + t] / cnt;
    __syncthreads();
    #pragma unroll
    for (int r = 0; r < 4; ++r) {
        int c = t + r * 64;
        float acc = b1[c];
        const float4* wr = (const float4*)(w1 + c * 64);
        const float4* gvv = (const float4*)gv;
        #pragma unroll
        for (int k = 0; k < 16; ++k) {
            float4 wv = wr[k], xv = gvv[k];
            acc += wv.x * xv.x + wv.y * xv.y + wv.z * xv.z + wv.w * xv.w;
        }
        hid[c] = fmaxf(acc, 0.0f);
    }
    __syncthreads();
    if (t < 16) {
        float acc = b2[t];
        const float4* wr = (const float4*)(w2 + t * 256);
        const float4* hv = (const float4*)hid;
        for (int k = 0; k < 64; ++k) {
            float4 wv = wr[k], xv = hv[k];
            acc += wv.x * xv.x + wv.y * xv.y + wv.z * xv.z + wv.w * xv.w;
        }
        outv[t] = acc;
    }
    __syncthreads();
    if (t < 16) {
        float m = outv[0];
        #pragma unroll
        for (int j = 1; j < 16; ++j) m = fmaxf(m, outv[j]);
        float ssum = 0.0f;
        #pragma unroll
        for (int j = 0; j < 16; ++j) ssum += expf(outv[j] - m);
        out[g * 16 + t] = outv[t] - m - logf(ssum);
    }
}

extern "C" void kernel_launch(void* const* d_in, const int* in_sizes, int n_in,
                              void* d_out, int out_size, void* d_ws, size_t ws_size,
                              hipStream_t stream)
{
    const float* x     = (const float*)d_in[0];
    const int*   ei    = (const int*)d_in[1];
    const float* ea    = (const float*)d_in[2];
    const int*   batch = (const int*)d_in[3];
    const float* wf1 = (const float*)d_in[4];
    const float* bf1 = (const float*)d_in[5];
    const float* ws1 = (const float*)d_in[6];
    const float* bs1 = (const float*)d_in[7];
    const float* wf2 = (const float*)d_in[8];
    const float* bf2 = (const float*)d_in[9];
    const float* ws2 = (const float*)d_in[10];
    const float* bs2 = (const float*)d_in[11];
    const float* w1 = (const float*)d_in[12];
    const float* b1 = (const float*)d_in[13];
    const float* w2 = (const float*)d_in[14];
    const float* b2 = (const float*)d_in[15];
    float* out = (float*)d_out;

    char* ws = (char*)d_ws;
    int*   cnt    = (int*)(ws + 0x0000000);           // 200 KB
    int*   cursor = (int*)(ws + 0x0040000);           // 200 KB
    float* invdeg = (float*)(ws + 0x0080000);         // 200 KB
    int*   bsum   = (int*)(ws + 0x00C0000);           // 1 KB
    int*   boffs  = (int*)(ws + 0x00C1000);           // 1 KB
    int2*  sed    = (int2*)(ws + 0x0100000);          // 12.8 MB
    unsigned short* xb  = (unsigned short*)(ws + 0x1500000);  // 6.4 MB
    unsigned short* hb  = (unsigned short*)(ws + 0x1C00000);  // 6.4 MB
    float* agg = (float*)(ws + 0x2300000);            // 12.8 MB
    unsigned short* wb1 = (unsigned short*)(ws + 0x3000000);  // 40 KB
    unsigned short* wb2 = (unsigned short*)(ws + 0x3010000);  // 40 KB
    float* gsum = (float*)(ws + 0x3020000);           // 128 KB
    float* gcnt = (float*)(ws + 0x3040000);           // 2 KB
    unsigned short* eab = (unsigned short*)(ws + 0x3100000);  // 102.4 MB (fits: rounds 8-11 ran this path)

    hipMemsetAsync(cnt, 0, 200000, stream);
    hipMemsetAsync(agg, 0, 12800000, stream);
    hipMemsetAsync(gsum, 0, 131072 + 2048, stream);

    prep_w_kernel<<<80, 256, 0, stream>>>(wf1, ws1, wf2, ws2, wb1, wb2);
    prep_x_kernel<<<3125, 256, 0, stream>>>((const float4*)x, xb);
    hist_kernel<<<6250, 256, 0, stream>>>(ei, cnt);
    bsum_kernel<<<NBS, 256, 0, stream>>>(cnt, bsum);
    bscan_kernel<<<1, 256, 0, stream>>>(bsum, boffs);
    apply_kernel<<<NBS, 256, 0, stream>>>(cnt, boffs, cursor, invdeg);
    scatter_kernel<<<6250, 256, 0, stream>>>(ei, cursor, ea, sed, eab);

    edge_mfma<<<1024, 256, 0, stream>>>(xb, sed, eab, wb1, bf1, bs1, agg);
    resid2_kernel<<<3125, 256, 0, stream>>>((const float4*)agg, invdeg, (const float4*)x, hb);
    hipMemsetAsync(agg, 0, 12800000, stream);
    edge_mfma<<<1024, 256, 0, stream>>>(hb, sed, eab, wb2, bf2, bs2, agg);
    pool2_kernel<<<782, 256, 0, stream>>>(agg, invdeg, hb, batch, gsum, gcnt);
    head_kernel<<<NUM_GRAPHS, 64, 0, stream>>>(gsum, gcnt, w1, b1, w2, b2, out);
}

// Round 14
// 610.353 us; speedup vs baseline: 1.0196x; 1.0196x over previous
//
#include <hip/hip_runtime.h>
#include <hip/hip_bf16.h>

#define N_NODES 50000
#define N_EDGES 1600000
#define IN_CH 64
#define NUM_HID 256
#define NUM_CLASSES 16
#define NUM_GRAPHS 512
#define NBS 196  // ceil(N_NODES/256)

typedef short bf16x8 __attribute__((ext_vector_type(8)));
typedef float f32x4 __attribute__((ext_vector_type(4)));

#if __has_builtin(__builtin_amdgcn_rcpf)
#define RCPF(x) __builtin_amdgcn_rcpf(x)
#else
#define RCPF(x) (1.0f / (x))
#endif

__device__ inline unsigned short f2b(float f) {
    unsigned int u = __float_as_uint(f);
    unsigned int r = (u + 0x7FFF + ((u >> 16) & 1)) >> 16;
    return (unsigned short)r;
}
__device__ inline float b2f(unsigned short u) {
    return __uint_as_float(((unsigned int)u) << 16);
}

// 16B global -> LDS direct; LDS dest = wave-uniform base + lane*16 (proven r9)
__device__ inline void gl16(const unsigned short* g, unsigned short* l) {
    __builtin_amdgcn_global_load_lds(
        (const __attribute__((address_space(1))) unsigned int*)g,
        (__attribute__((address_space(3))) unsigned int*)l, 16, 0, 0);
}

// ---------------- preprocessing ----------------
__global__ void prep_w_kernel(const float* __restrict__ wf1, const float* __restrict__ ws1,
                              const float* __restrict__ wf2, const float* __restrict__ ws2,
                              unsigned short* __restrict__ wb1, unsigned short* __restrict__ wb2) {
    int i = blockIdx.x * 256 + threadIdx.x;
    if (i >= 128 * 160) return;
    int r = i / 160, k = i - r * 160;
    wb1[i] = f2b(r < 64 ? wf1[r * 160 + k] : ws1[(r - 64) * 160 + k]);
    wb2[i] = f2b(r < 64 ? wf2[r * 160 + k] : ws2[(r - 64) * 160 + k]);
}

__global__ void prep_x_kernel(const float4* __restrict__ x, unsigned short* __restrict__ xb) {
    int i = blockIdx.x * 256 + threadIdx.x;
    if (i >= N_NODES * 16) return;
    float4 v = x[i];
    ushort4 u; u.x = f2b(v.x); u.y = f2b(v.y); u.z = f2b(v.z); u.w = f2b(v.w);
    *(ushort4*)(xb + i * 4) = u;
}

__global__ void hist_kernel(const int* __restrict__ ei, int* __restrict__ cnt) {
    int i = blockIdx.x * 256 + threadIdx.x;
    if (i < N_EDGES) atomicAdd(&cnt[ei[N_EDGES + i]], 1);
}

__global__ void bsum_kernel(const int* __restrict__ cnt, int* __restrict__ bsum) {
    __shared__ int sm[256];
    int i = blockIdx.x * 256 + threadIdx.x;
    sm[threadIdx.x] = (i < N_NODES) ? cnt[i] : 0;
    __syncthreads();
    for (int off = 128; off > 0; off >>= 1) {
        if (threadIdx.x < off) sm[threadIdx.x] += sm[threadIdx.x + off];
        __syncthreads();
    }
    if (threadIdx.x == 0) bsum[blockIdx.x] = sm[0];
}

__global__ void bscan_kernel(const int* __restrict__ bsum, int* __restrict__ boffs) {
    __shared__ int sm[256];
    int t = threadIdx.x;
    int v = (t < NBS) ? bsum[t] : 0;
    sm[t] = v; __syncthreads();
    for (int off = 1; off < 256; off <<= 1) {
        int u = (t >= off) ? sm[t - off] : 0;
        __syncthreads();
        sm[t] += u;
        __syncthreads();
    }
    if (t < NBS) boffs[t] = sm[t] - v;  // exclusive
}

__global__ void apply_kernel(const int* __restrict__ cnt, const int* __restrict__ boffs,
                             int* __restrict__ cursor, float* __restrict__ invdeg) {
    __shared__ int sm[256];
    int t = threadIdx.x, i = blockIdx.x * 256 + t;
    int c = (i < N_NODES) ? cnt[i] : 0;
    sm[t] = c; __syncthreads();
    for (int off = 1; off < 256; off <<= 1) {
        int u = (t >= off) ? sm[t - off] : 0;
        __syncthreads();
        sm[t] += u;
        __syncthreads();
    }
    if (i < N_NODES) {
        cursor[i] = boffs[blockIdx.x] + sm[t] - c;
        invdeg[i] = 1.0f / fmaxf((float)c, 1.0f);
    }
}

// scatter + in-place sort of edge_attr to dst-order (bf16), fused
__global__ void scatter_kernel(const int* __restrict__ ei, int* __restrict__ cursor,
                               const float* __restrict__ ea,
                               int2* __restrict__ sed, unsigned short* __restrict__ eab) {
    int e = blockIdx.x * 256 + threadIdx.x;
    if (e >= N_EDGES) return;
    int s = ei[e], d = ei[N_EDGES + e];
    int p = atomicAdd(&cursor[d], 1);
    sed[p] = make_int2(s, d);
    const float4* src = (const float4*)(ea + (size_t)e * 32);
    unsigned short* dst = eab + (size_t)p * 32;
    #pragma unroll
    for (int j = 0; j < 8; ++j) {
        float4 v = src[j];
        ushort4 u; u.x = f2b(v.x); u.y = f2b(v.y); u.z = f2b(v.z); u.w = f2b(v.w);
        *(ushort4*)(dst + j * 4) = u;
    }
}

// ---------------- edge pass: gload_lds staging, 1 barrier/tile ----------------
// Wave = 64 edges x 16 ch (B = 40 VGPR). No staging registers at all:
// tile t+1 staged direct-to-LDS at top of tile t (dest buffer idle since t-1).
__global__ __launch_bounds__(256, 2)
void edge_mfma(const unsigned short* __restrict__ xb,
               const int2* __restrict__ sed, const unsigned short* __restrict__ eab,
               const unsigned short* __restrict__ wb,
               const float* __restrict__ bfv, const float* __restrict__ bsv,
               float* __restrict__ agg)
{
    __shared__ __align__(16) unsigned short Zd[2][64 * 64];  // chunk c of row e holds data chunk c^(e&7)
    __shared__ __align__(16) unsigned short Zs[2][64 * 64];
    __shared__ __align__(16) unsigned short Ze[2][64 * 32];  // chunk c holds data chunk c^((e>>1)&3)
    // 40960 B total

    const int tid = threadIdx.x;
    const int w = tid >> 6, lane = tid & 63, lr = lane & 15, lq = lane >> 4;
    const int chw = w * 16;

    // B frags: both mats, one ch-quarter, 5 ks = 40 VGPR
    bf16x8 B[2][5];
    #pragma unroll
    for (int mat = 0; mat < 2; ++mat)
        #pragma unroll
        for (int ks = 0; ks < 5; ++ks)
            B[mat][ks] = *(const bf16x8*)(wb + (size_t)(mat * 64 + chw + lr) * 160 + ks * 32 + lq * 8);

    const float biasF = bfv[chw + lr];
    const float biasS = bsv[chw + lr];

    const int NT = N_EDGES / 64;
    const int nblk = gridDim.x;

    // Staging geometry (wave w stages rows [w*16, w*16+16)):
    //   Zd/Zs: 2 gloads x 8 rows; lane -> row_off = lane>>3, stored chunk = lane&7,
    //          data chunk = (lane&7)^(lane>>3)  [since (w*16 + r)&7 = r&7 = lane>>3]
    //   Ze: 1 gload x 16 rows; lane -> row_off = lane>>2, stored chunk = lane&3,
    //          data chunk = (lane&3)^((lane>>3)&3)
    #define STAGE(T, PAR) do { \
        int e0_ = (T) * 64; \
        int rb_ = w * 16 + (lane >> 3); \
        int dcA_ = (lane & 7) ^ (lane >> 3); \
        int2 s0_ = sed[e0_ + rb_]; \
        int2 s1_ = sed[e0_ + rb_ + 8]; \
        gl16(xb + (size_t)s0_.y * 64 + dcA_ * 8, &Zd[PAR][w * 1024]); \
        gl16(xb + (size_t)s1_.y * 64 + dcA_ * 8, &Zd[PAR][w * 1024 + 512]); \
        gl16(xb + (size_t)s0_.x * 64 + dcA_ * 8, &Zs[PAR][w * 1024]); \
        gl16(xb + (size_t)s1_.x * 64 + dcA_ * 8, &Zs[PAR][w * 1024 + 512]); \
        int rE_ = w * 16 + (lane >> 2); \
        int dcE_ = (lane & 3) ^ ((lane >> 3) & 3); \
        gl16(eab + (size_t)(e0_ + rE_) * 32 + dcE_ * 8, &Ze[PAR][w * 512]); \
    } while (0)

    int t = blockIdx.x;
    if (t < NT) STAGE(t, 0);
    __syncthreads();  // drains vmcnt -> tile 0 ready
    int par = 0;

    for (; t < NT; t += nblk) {
        int tn = t + nblk;
        if (tn < NT) STAGE(tn, par ^ 1);  // buffer par^1 idle since tile t-1; lands during this tile

        int dme = sed[t * 64 + lane].y;   // per-lane dst of current tile (coalesced)

        // ---- k-loop: all 64 edges x this wave's 16 ch, both mats ----
        f32x4 aF[4] = {}; f32x4 aS[4] = {};
        #pragma unroll
        for (int ks = 0; ks < 5; ++ks) {
            bf16x8 a[4];
            #pragma unroll
            for (int m = 0; m < 4; ++m) {
                const int rm = m * 16 + lr;
                if (ks < 2) {
                    int j = ks * 4 + lq;
                    a[m] = *(const bf16x8*)&Zd[par][rm * 64 + ((j ^ (rm & 7)) * 8)];
                } else if (ks < 4) {
                    int j = (ks - 2) * 4 + lq;
                    a[m] = *(const bf16x8*)&Zs[par][rm * 64 + ((j ^ (rm & 7)) * 8)];
                } else {
                    a[m] = *(const bf16x8*)&Ze[par][rm * 32 + ((lq ^ ((rm >> 1) & 3)) * 8)];
                }
            }
            #pragma unroll
            for (int m = 0; m < 4; ++m) {
                aF[m] = __builtin_amdgcn_mfma_f32_16x16x32_bf16(a[m], B[0][ks], aF[m], 0, 0, 0);
                aS[m] = __builtin_amdgcn_mfma_f32_16x16x32_bf16(a[m], B[1][ks], aS[m], 0, 0, 0);
            }
        }

        // ---- activation in registers ----
        float val[16];   // row r = m*16 + lq*4 + i, ch = chw + lr
        #pragma unroll
        for (int m = 0; m < 4; ++m)
            #pragma unroll
            for (int i = 0; i < 4; ++i) {
                float f = aF[m][i] + biasF;
                float s = aS[m][i] + biasS;
                float sig = RCPF(1.0f + __expf(-f));
                float sp = fmaxf(s, 0.0f) + __logf(1.0f + __expf(-fabsf(s)));
                val[m * 4 + i] = sig * sp;
            }

        // ---- in-register segmented run-reduction over 64 edges ----
        {
            int dprev = __shfl(dme, lane - 1);
            unsigned long long bmask = __ballot((lane == 0) || (dme != dprev));
            while (bmask) {
                int lo = (int)__builtin_ctzll(bmask);
                bmask &= bmask - 1;
                int hi = bmask ? (int)__builtin_ctzll(bmask) : 64;
                int dst = __shfl(dme, lo);   // wave-uniform
                float t0 = 0.0f;
                #pragma unroll
                for (int m = 0; m < 4; ++m)
                    #pragma unroll
                    for (int i = 0; i < 4; ++i) {
                        int r = m * 16 + lq * 4 + i;
                        t0 += ((r >= lo) && (r < hi)) ? val[m * 4 + i] : 0.0f;
                    }
                t0 += __shfl_xor(t0, 16);
                t0 += __shfl_xor(t0, 32);
                if (lq == 0)
                    atomicAdd(&agg[(size_t)dst * 64 + chw + lr], t0);
            }
        }

        __syncthreads();  // single barrier: staged tile landed + visible; par flips
        par ^= 1;
    }
    #undef STAGE
}

// ---------------- residual: hb = bf16(agg*inv_deg + x) ----------------
__global__ void resid2_kernel(const float4* __restrict__ agg, const float* __restrict__ inv_deg,
                              const float4* __restrict__ x, unsigned short* __restrict__ hb)
{
    int i = blockIdx.x * 256 + threadIdx.x;
    if (i >= N_NODES * 16) return;
    int n = i >> 4;
    float iv = inv_deg[n];
    float4 a = agg[i], xv = x[i];
    ushort4 u;
    u.x = f2b(a.x * iv + xv.x); u.y = f2b(a.y * iv + xv.y);
    u.z = f2b(a.z * iv + xv.z); u.w = f2b(a.w * iv + xv.w);
    *(ushort4*)(hb + i * 4) = u;
}

// ---------------- layer-2 residual + pooling: run-reduction over SORTED batch ----------------
__global__ void pool2_kernel(const float* __restrict__ agg, const float* __restrict__ inv_deg,
                             const unsigned short* __restrict__ hb, const int* __restrict__ batch,
                             float* __restrict__ gsum, float* __restrict__ gcnt)
{
    const int ch = threadIdx.x & 63, sub = threadIdx.x >> 6;
    const int base = blockIdx.x * 64 + sub * 16;
    float acc = 0.0f;
    int gcur = -1, rl = 0;
    #pragma unroll
    for (int j = 0; j < 16; ++j) {
        int n = base + j;
        if (n >= N_NODES) break;
        int g = batch[n];
        float v = agg[(size_t)n * 64 + ch] * inv_deg[n] + b2f(hb[(size_t)n * 64 + ch]);
        if (g != gcur) {
            if (gcur >= 0) {
                atomicAdd(&gsum[gcur * 64 + ch], acc);
                if (ch == 0) atomicAdd(&gcnt[gcur], (float)rl);
            }
            gcur = g; acc = v; rl = 1;
        } else {
            acc += v; rl++;
        }
    }
    if (gcur >= 0) {
        atomicAdd(&gsum[gcur * 64 + ch], acc);
        if (ch == 0) atomicAdd(&gcnt[gcur], (float)rl);
    }
}

// ---------------- head: MLP + log_softmax ----------------
__global__ __launch_bounds__(64)
void head_kernel(const float* __restrict__ gsum, const float* __restrict__ gcnt,
                 const float* __restrict__ w1, const float* __restrict__ b1,
                 const float* __restrict__ w2, const float* __restrict__ b2,
                 float* __restrict__ out)
{
    __shared__ float gv[64];
    __shared__ float hid[256];
    __shared__ float outv[16];
    const int g = blockIdx.x, t = threadIdx.x;
    float cnt = fmaxf(gcnt[g], 1.0f);
    gv[t] = gsum[g * 64 + t] / cnt;
    __syncthreads();
    #pragma unroll
    for (int r = 0; r < 4; ++r) {
        int c = t + r * 64;
        float acc = b1[c];
        const float4* wr = (const float4*)(w1 + c * 64);
        const float4* gvv = (const float4*)gv;
        #pragma unroll
        for (int k = 0; k < 16; ++k) {
            float4 wv = wr[k], xv = gvv[k];
            acc += wv.x * xv.x + wv.y * xv.y + wv.z * xv.z + wv.w * xv.w;
        }
        hid[c] = fmaxf(acc, 0.0f);
    }
    __syncthreads();
    if (t < 16) {
        float acc = b2[t];
        const float4* wr = (const float4*)(w2 + t * 256);
        const float4* hv = (const float4*)hid;
        for (int k = 0; k < 64; ++k) {
            float4 wv = wr[k], xv = hv[k];
            acc += wv.x * xv.x + wv.y * xv.y + wv.z * xv.z + wv.w * xv.w;
        }
        outv[t] = acc;
    }
    __syncthreads();
    if (t < 16) {
        float m = outv[0];
        #pragma unroll
        for (int j = 1; j < 16; ++j) m = fmaxf(m, outv[j]);
        float ssum = 0.0f;
        #pragma unroll
        for (int j = 0; j < 16; ++j) ssum += expf(outv[j] - m);
        out[g * 16 + t] = outv[t] - m - logf(ssum);
    }
}

extern "C" void kernel_launch(void* const* d_in, const int* in_sizes, int n_in,
                              void* d_out, int out_size, void* d_ws, size_t ws_size,
                              hipStream_t stream)
{
    const float* x     = (const float*)d_in[0];
    const int*   ei    = (const int*)d_in[1];
    const float* ea    = (const float*)d_in[2];
    const int*   batch = (const int*)d_in[3];
    const float* wf1 = (const float*)d_in[4];
    const float* bf1 = (const float*)d_in[5];
    const float* ws1 = (const float*)d_in[6];
    const float* bs1 = (const float*)d_in[7];
    const float* wf2 = (const float*)d_in[8];
    const float* bf2 = (const float*)d_in[9];
    const float* ws2 = (const float*)d_in[10];
    const float* bs2 = (const float*)d_in[11];
    const float* w1 = (const float*)d_in[12];
    const float* b1 = (const float*)d_in[13];
    const float* w2 = (const float*)d_in[14];
    const float* b2 = (const float*)d_in[15];
    float* out = (float*)d_out;

    char* ws = (char*)d_ws;
    int*   cnt    = (int*)(ws + 0x0000000);           // 200 KB
    int*   cursor = (int*)(ws + 0x0040000);           // 200 KB
    float* invdeg = (float*)(ws + 0x0080000);         // 200 KB
    int*   bsum   = (int*)(ws + 0x00C0000);           // 1 KB
    int*   boffs  = (int*)(ws + 0x00C1000);           // 1 KB
    int2*  sed    = (int2*)(ws + 0x0100000);          // 12.8 MB
    unsigned short* xb  = (unsigned short*)(ws + 0x1500000);  // 6.4 MB
    unsigned short* hb  = (unsigned short*)(ws + 0x1C00000);  // 6.4 MB
    float* agg = (float*)(ws + 0x2300000);            // 12.8 MB
    unsigned short* wb1 = (unsigned short*)(ws + 0x3000000);  // 40 KB
    unsigned short* wb2 = (unsigned short*)(ws + 0x3010000);  // 40 KB
    float* gsum = (float*)(ws + 0x3020000);           // 128 KB
    float* gcnt = (float*)(ws + 0x3040000);           // 2 KB
    unsigned short* eab = (unsigned short*)(ws + 0x3100000);  // 102.4 MB (fits: r8-r12 ran this)

    hipMemsetAsync(cnt, 0, 200000, stream);
    hipMemsetAsync(agg, 0, 12800000, stream);
    hipMemsetAsync(gsum, 0, 131072 + 2048, stream);

    prep_w_kernel<<<80, 256, 0, stream>>>(wf1, ws1, wf2, ws2, wb1, wb2);
    prep_x_kernel<<<3125, 256, 0, stream>>>((const float4*)x, xb);
    hist_kernel<<<6250, 256, 0, stream>>>(ei, cnt);
    bsum_kernel<<<NBS, 256, 0, stream>>>(cnt, bsum);
    bscan_kernel<<<1, 256, 0, stream>>>(bsum, boffs);
    apply_kernel<<<NBS, 256, 0, stream>>>(cnt, boffs, cursor, invdeg);
    scatter_kernel<<<6250, 256, 0, stream>>>(ei, cursor, ea, sed, eab);

    edge_mfma<<<1024, 256, 0, stream>>>(xb, sed, eab, wb1, bf1, bs1, agg);
    resid2_kernel<<<3125, 256, 0, stream>>>((const float4*)agg, invdeg, (const float4*)x, hb);
    hipMemsetAsync(agg, 0, 12800000, stream);
    edge_mfma<<<1024, 256, 0, stream>>>(hb, sed, eab, wb2, bf2, bs2, agg);
    pool2_kernel<<<782, 256, 0, stream>>>(agg, invdeg, hb, batch, gsum, gcnt);
    head_kernel<<<NUM_GRAPHS, 64, 0, stream>>>(gsum, gcnt, w1, b1, w2, b2, out);
}

// Round 15
// 596.562 us; speedup vs baseline: 1.0432x; 1.0231x over previous
//
#include <hip/hip_runtime.h>
#include <hip/hip_bf16.h>

#define N_NODES 50000
#define N_EDGES 1600000
#define IN_CH 64
#define NUM_HID 256
#define NUM_CLASSES 16
#define NUM_GRAPHS 512
#define NBS 196  // ceil(N_NODES/256)

typedef short bf16x8 __attribute__((ext_vector_type(8)));
typedef float f32x4 __attribute__((ext_vector_type(4)));

#if __has_builtin(__builtin_amdgcn_rcpf)
#define RCPF(x) __builtin_amdgcn_rcpf(x)
#else
#define RCPF(x) (1.0f / (x))
#endif

__device__ inline unsigned short f2b(float f) {
    unsigned int u = __float_as_uint(f);
    unsigned int r = (u + 0x7FFF + ((u >> 16) & 1)) >> 16;
    return (unsigned short)r;
}
__device__ inline float b2f(unsigned short u) {
    return __uint_as_float(((unsigned int)u) << 16);
}

// 16B global -> LDS direct; LDS dest = wave-uniform base + lane*16 (proven r9/r14)
__device__ inline void gl16(const unsigned short* g, unsigned short* l) {
    __builtin_amdgcn_global_load_lds(
        (const __attribute__((address_space(1))) unsigned int*)g,
        (__attribute__((address_space(3))) unsigned int*)l, 16, 0, 0);
}

// ---------------- preprocessing ----------------
__global__ void prep_w_kernel(const float* __restrict__ wf1, const float* __restrict__ ws1,
                              const float* __restrict__ wf2, const float* __restrict__ ws2,
                              unsigned short* __restrict__ wb1, unsigned short* __restrict__ wb2) {
    int i = blockIdx.x * 256 + threadIdx.x;
    if (i >= 128 * 160) return;
    int r = i / 160, k = i - r * 160;
    wb1[i] = f2b(r < 64 ? wf1[r * 160 + k] : ws1[(r - 64) * 160 + k]);
    wb2[i] = f2b(r < 64 ? wf2[r * 160 + k] : ws2[(r - 64) * 160 + k]);
}

__global__ void prep_x_kernel(const float4* __restrict__ x, unsigned short* __restrict__ xb) {
    int i = blockIdx.x * 256 + threadIdx.x;
    if (i >= N_NODES * 16) return;
    float4 v = x[i];
    ushort4 u; u.x = f2b(v.x); u.y = f2b(v.y); u.z = f2b(v.z); u.w = f2b(v.w);
    *(ushort4*)(xb + i * 4) = u;
}

__global__ void hist_kernel(const int* __restrict__ ei, int* __restrict__ cnt) {
    int i = blockIdx.x * 256 + threadIdx.x;
    if (i < N_EDGES) atomicAdd(&cnt[ei[N_EDGES + i]], 1);
}

__global__ void bsum_kernel(const int* __restrict__ cnt, int* __restrict__ bsum) {
    __shared__ int sm[256];
    int i = blockIdx.x * 256 + threadIdx.x;
    sm[threadIdx.x] = (i < N_NODES) ? cnt[i] : 0;
    __syncthreads();
    for (int off = 128; off > 0; off >>= 1) {
        if (threadIdx.x < off) sm[threadIdx.x] += sm[threadIdx.x + off];
        __syncthreads();
    }
    if (threadIdx.x == 0) bsum[blockIdx.x] = sm[0];
}

__global__ void bscan_kernel(const int* __restrict__ bsum, int* __restrict__ boffs) {
    __shared__ int sm[256];
    int t = threadIdx.x;
    int v = (t < NBS) ? bsum[t] : 0;
    sm[t] = v; __syncthreads();
    for (int off = 1; off < 256; off <<= 1) {
        int u = (t >= off) ? sm[t - off] : 0;
        __syncthreads();
        sm[t] += u;
        __syncthreads();
    }
    if (t < NBS) boffs[t] = sm[t] - v;  // exclusive
}

__global__ void apply_kernel(const int* __restrict__ cnt, const int* __restrict__ boffs,
                             int* __restrict__ cursor, float* __restrict__ invdeg) {
    __shared__ int sm[256];
    int t = threadIdx.x, i = blockIdx.x * 256 + t;
    int c = (i < N_NODES) ? cnt[i] : 0;
    sm[t] = c; __syncthreads();
    for (int off = 1; off < 256; off <<= 1) {
        int u = (t >= off) ? sm[t - off] : 0;
        __syncthreads();
        sm[t] += u;
        __syncthreads();
    }
    if (i < N_NODES) {
        cursor[i] = boffs[blockIdx.x] + sm[t] - c;
        invdeg[i] = 1.0f / fmaxf((float)c, 1.0f);
    }
}

// scatter + in-place sort of edge_attr to dst-order (bf16), fused
__global__ void scatter_kernel(const int* __restrict__ ei, int* __restrict__ cursor,
                               const float* __restrict__ ea,
                               int2* __restrict__ sed, unsigned short* __restrict__ eab) {
    int e = blockIdx.x * 256 + threadIdx.x;
    if (e >= N_EDGES) return;
    int s = ei[e], d = ei[N_EDGES + e];
    int p = atomicAdd(&cursor[d], 1);
    sed[p] = make_int2(s, d);
    const float4* src = (const float4*)(ea + (size_t)e * 32);
    unsigned short* dst = eab + (size_t)p * 32;
    #pragma unroll
    for (int j = 0; j < 8; ++j) {
        float4 v = src[j];
        ushort4 u; u.x = f2b(v.x); u.y = f2b(v.y); u.z = f2b(v.z); u.w = f2b(v.w);
        *(ushort4*)(dst + j * 4) = u;
    }
}

// ---------------- edge pass: gload_lds staging + msg-LDS serial reduce ----------------
// Wave = 64 edges x 16 ch, B = 40 VGPR, no staging registers (direct-to-LDS DMA).
// Reduce: act -> msg LDS; wave w serially reduces edges [w*16,w*16+16) x 64 ch
// (dst compare wave-uniform -> scalar branch; LDS pipe does the data movement).
__global__ __launch_bounds__(256, 2)
void edge_mfma(const unsigned short* __restrict__ xb,
               const int2* __restrict__ sed, const unsigned short* __restrict__ eab,
               const unsigned short* __restrict__ wb,
               const float* __restrict__ bfv, const float* __restrict__ bsv,
               float* __restrict__ agg)
{
    __shared__ __align__(16) unsigned short Zd[2][64 * 64];  // chunk c of row e holds data chunk c^(e&7)
    __shared__ __align__(16) unsigned short Zs[2][64 * 64];
    __shared__ __align__(16) unsigned short Ze[2][64 * 32];  // chunk c holds data chunk c^((e>>1)&3)
    __shared__ float msg[64 * 68];                           // [edge][ch], stride 68 (2-way banks = free)
    __shared__ int dstl[2][64];

    const int tid = threadIdx.x;
    const int w = tid >> 6, lane = tid & 63, lr = lane & 15, lq = lane >> 4;
    const int chw = w * 16;

    // B frags: both mats, one ch-quarter, 5 ks = 40 VGPR
    bf16x8 B[2][5];
    #pragma unroll
    for (int mat = 0; mat < 2; ++mat)
        #pragma unroll
        for (int ks = 0; ks < 5; ++ks)
            B[mat][ks] = *(const bf16x8*)(wb + (size_t)(mat * 64 + chw + lr) * 160 + ks * 32 + lq * 8);

    const float biasF = bfv[chw + lr];
    const float biasS = bsv[chw + lr];

    const int NT = N_EDGES / 64;
    const int nblk = gridDim.x;

    // Staging (wave w stages rows [w*16, w*16+16)):
    //   Zd/Zs: 2 gloads x 8 rows; lane -> row_off = lane>>3, stored chunk = lane&7,
    //          data chunk = (lane&7)^(lane>>3)
    //   Ze: 1 gload x 16 rows; lane -> row_off = lane>>2, stored chunk = lane&3,
    //          data chunk = (lane&3)^((lane>>3)&3)
    #define STAGE(T, PAR) do { \
        int e0_ = (T) * 64; \
        int rb_ = w * 16 + (lane >> 3); \
        int dcA_ = (lane & 7) ^ (lane >> 3); \
        int2 s0_ = sed[e0_ + rb_]; \
        int2 s1_ = sed[e0_ + rb_ + 8]; \
        gl16(xb + (size_t)s0_.y * 64 + dcA_ * 8, &Zd[PAR][w * 1024]); \
        gl16(xb + (size_t)s1_.y * 64 + dcA_ * 8, &Zd[PAR][w * 1024 + 512]); \
        gl16(xb + (size_t)s0_.x * 64 + dcA_ * 8, &Zs[PAR][w * 1024]); \
        gl16(xb + (size_t)s1_.x * 64 + dcA_ * 8, &Zs[PAR][w * 1024 + 512]); \
        int rE_ = w * 16 + (lane >> 2); \
        int dcE_ = (lane & 3) ^ ((lane >> 3) & 3); \
        gl16(eab + (size_t)(e0_ + rE_) * 32 + dcE_ * 8, &Ze[PAR][w * 512]); \
        if (tid < 64) dstl[PAR][tid] = sed[e0_ + tid].y; \
    } while (0)

    #define SOFT_BARRIER() do { \
        asm volatile("s_waitcnt lgkmcnt(0)" ::: "memory"); \
        __builtin_amdgcn_s_barrier(); \
    } while (0)

    int t = blockIdx.x;
    if (t < NT) STAGE(t, 0);
    __syncthreads();  // drains vmcnt -> tile 0 ready
    int par = 0;

    for (; t < NT; t += nblk) {
        int tn = t + nblk;
        if (tn < NT) STAGE(tn, par ^ 1);  // buffer par^1 idle since t-1; DMA lands during this tile

        // ---- k-loop: all 64 edges x this wave's 16 ch, both mats ----
        f32x4 aF[4] = {}; f32x4 aS[4] = {};
        #pragma unroll
        for (int ks = 0; ks < 5; ++ks) {
            bf16x8 a[4];
            #pragma unroll
            for (int m = 0; m < 4; ++m) {
                const int rm = m * 16 + lr;
                if (ks < 2) {
                    int j = ks * 4 + lq;
                    a[m] = *(const bf16x8*)&Zd[par][rm * 64 + ((j ^ (rm & 7)) * 8)];
                } else if (ks < 4) {
                    int j = (ks - 2) * 4 + lq;
                    a[m] = *(const bf16x8*)&Zs[par][rm * 64 + ((j ^ (rm & 7)) * 8)];
                } else {
                    a[m] = *(const bf16x8*)&Ze[par][rm * 32 + ((lq ^ ((rm >> 1) & 3)) * 8)];
                }
            }
            #pragma unroll
            for (int m = 0; m < 4; ++m) {
                aF[m] = __builtin_amdgcn_mfma_f32_16x16x32_bf16(a[m], B[0][ks], aF[m], 0, 0, 0);
                aS[m] = __builtin_amdgcn_mfma_f32_16x16x32_bf16(a[m], B[1][ks], aS[m], 0, 0, 0);
            }
        }

        // ---- activation -> msg LDS (direct write, no val[] array) ----
        #pragma unroll
        for (int m = 0; m < 4; ++m)
            #pragma unroll
            for (int i = 0; i < 4; ++i) {
                float f = aF[m][i] + biasF;
                float s = aS[m][i] + biasS;
                float sig = RCPF(1.0f + __expf(-f));
                float sp = fmaxf(s, 0.0f) + __logf(1.0f + __expf(-fabsf(s)));
                msg[(m * 16 + lq * 4 + i) * 68 + chw + lr] = sig * sp;
            }
        SOFT_BARRIER();  // lgkm only: msg + dstl visible; staging DMAs stay in flight

        // ---- serial run-reduction: wave w owns edges [w*16, w*16+16), channel = lane ----
        {
            float acc = 0.0f;
            int dcur = dstl[par][w * 16];
            #pragma unroll
            for (int j = 0; j < 16; ++j) {
                int e = w * 16 + j;
                int d = dstl[par][e];           // wave-uniform broadcast
                float v = msg[e * 68 + lane];
                if (d != dcur) {                // wave-uniform -> scalar branch
                    atomicAdd(&agg[(size_t)dcur * 64 + lane], acc);
                    dcur = d; acc = v;
                } else {
                    acc += v;
                }
            }
            atomicAdd(&agg[(size_t)dcur * 64 + lane], acc);
        }

        __syncthreads();  // drains vmcnt: staged tile landed; msg safe to overwrite
        par ^= 1;
    }
    #undef STAGE
    #undef SOFT_BARRIER
}

// ---------------- residual: hb = bf16(agg*inv_deg + x) ----------------
__global__ void resid2_kernel(const float4* __restrict__ agg, const float* __restrict__ inv_deg,
                              const float4* __restrict__ x, unsigned short* __restrict__ hb)
{
    int i = blockIdx.x * 256 + threadIdx.x;
    if (i >= N_NODES * 16) return;
    int n = i >> 4;
    float iv = inv_deg[n];
    float4 a = agg[i], xv = x[i];
    ushort4 u;
    u.x = f2b(a.x * iv + xv.x); u.y = f2b(a.y * iv + xv.y);
    u.z = f2b(a.z * iv + xv.z); u.w = f2b(a.w * iv + xv.w);
    *(ushort4*)(hb + i * 4) = u;
}

// ---------------- layer-2 residual + pooling: run-reduction over SORTED batch ----------------
__global__ void pool2_kernel(const float* __restrict__ agg, const float* __restrict__ inv_deg,
                             const unsigned short* __restrict__ hb, const int* __restrict__ batch,
                             float* __restrict__ gsum, float* __restrict__ gcnt)
{
    const int ch = threadIdx.x & 63, sub = threadIdx.x >> 6;
    const int base = blockIdx.x * 64 + sub * 16;
    float acc = 0.0f;
    int gcur = -1, rl = 0;
    #pragma unroll
    for (int j = 0; j < 16; ++j) {
        int n = base + j;
        if (n >= N_NODES) break;
        int g = batch[n];
        float v = agg[(size_t)n * 64 + ch] * inv_deg[n] + b2f(hb[(size_t)n * 64 + ch]);
        if (g != gcur) {
            if (gcur >= 0) {
                atomicAdd(&gsum[gcur * 64 + ch], acc);
                if (ch == 0) atomicAdd(&gcnt[gcur], (float)rl);
            }
            gcur = g; acc = v; rl = 1;
        } else {
            acc += v; rl++;
        }
    }
    if (gcur >= 0) {
        atomicAdd(&gsum[gcur * 64 + ch], acc);
        if (ch == 0) atomicAdd(&gcnt[gcur], (float)rl);
    }
}

// ---------------- head: MLP + log_softmax ----------------
__global__ __launch_bounds__(64)
void head_kernel(const float* __restrict__ gsum, const float* __restrict__ gcnt,
                 const float* __restrict__ w1, const float* __restrict__ b1,
                 const float* __restrict__ w2, const float* __restrict__ b2,
                 float* __restrict__ out)
{
    __shared__ float gv[64];
    __shared__ float hid[256];
    __shared__ float outv[16];
    const int g = blockIdx.x, t = threadIdx.x;
    float cnt = fmaxf(gcnt[g], 1.0f);
    gv[t] = gsum[g * 64 + t] / cnt;
    __syncthreads();
    #pragma unroll
    for (int r = 0; r < 4; ++r) {
        int c = t + r * 64;
        float acc = b1[c];
        const float4* wr = (const float4*)(w1 + c * 64);
        const float4* gvv = (const float4*)gv;
        #pragma unroll
        for (int k = 0; k < 16; ++k) {
            float4 wv = wr[k], xv = gvv[k];
            acc += wv.x * xv.x + wv.y * xv.y + wv.z * xv.z + wv.w * xv.w;
        }
        hid[c] = fmaxf(acc, 0.0f);
    }
    __syncthreads();
    if (t < 16) {
        float acc = b2[t];
        const float4* wr = (const float4*)(w2 + t * 256);
        const float4* hv = (const float4*)hid;
        for (int k = 0; k < 64; ++k) {
            float4 wv = wr[k], xv = hv[k];
            acc += wv.x * xv.x + wv.y * xv.y + wv.z * xv.z + wv.w * xv.w;
        }
        outv[t] = acc;
    }
    __syncthreads();
    if (t < 16) {
        float m = outv[0];
        #pragma unroll
        for (int j = 1; j < 16; ++j) m = fmaxf(m, outv[j]);
        float ssum = 0.0f;
        #pragma unroll
        for (int j = 0; j < 16; ++j) ssum += expf(outv[j] - m);
        out[g * 16 + t] = outv[t] - m - logf(ssum);
    }
}

extern "C" void kernel_launch(void* const* d_in, const int* in_sizes, int n_in,
                              void* d_out, int out_size, void* d_ws, size_t ws_size,
                              hipStream_t stream)
{
    const float* x     = (const float*)d_in[0];
    const int*   ei    = (const int*)d_in[1];
    const float* ea    = (const float*)d_in[2];
    const int*   batch = (const int*)d_in[3];
    const float* wf1 = (const float*)d_in[4];
    const float* bf1 = (const float*)d_in[5];
    const float* ws1 = (const float*)d_in[6];
    const float* bs1 = (const float*)d_in[7];
    const float* wf2 = (const float*)d_in[8];
    const float* bf2 = (const float*)d_in[9];
    const float* ws2 = (const float*)d_in[10];
    const float* bs2 = (const float*)d_in[11];
    const float* w1 = (const float*)d_in[12];
    const float* b1 = (const float*)d_in[13];
    const float* w2 = (const float*)d_in[14];
    const float* b2 = (const float*)d_in[15];
    float* out = (float*)d_out;

    char* ws = (char*)d_ws;
    int*   cnt    = (int*)(ws + 0x0000000);           // 200 KB
    int*   cursor = (int*)(ws + 0x0040000);           // 200 KB
    float* invdeg = (float*)(ws + 0x0080000);         // 200 KB
    int*   bsum   = (int*)(ws + 0x00C0000);           // 1 KB
    int*   boffs  = (int*)(ws + 0x00C1000);           // 1 KB
    int2*  sed    = (int2*)(ws + 0x0100000);          // 12.8 MB
    unsigned short* xb  = (unsigned short*)(ws + 0x1500000);  // 6.4 MB
    unsigned short* hb  = (unsigned short*)(ws + 0x1C00000);  // 6.4 MB
    float* agg = (float*)(ws + 0x2300000);            // 12.8 MB
    unsigned short* wb1 = (unsigned short*)(ws + 0x3000000);  // 40 KB
    unsigned short* wb2 = (unsigned short*)(ws + 0x3010000);  // 40 KB
    float* gsum = (float*)(ws + 0x3020000);           // 128 KB
    float* gcnt = (float*)(ws + 0x3040000);           // 2 KB
    unsigned short* eab = (unsigned short*)(ws + 0x3100000);  // 102.4 MB (fits: r8-r14 ran this)

    hipMemsetAsync(cnt, 0, 200000, stream);
    hipMemsetAsync(agg, 0, 12800000, stream);
    hipMemsetAsync(gsum, 0, 131072 + 2048, stream);

    prep_w_kernel<<<80, 256, 0, stream>>>(wf1, ws1, wf2, ws2, wb1, wb2);
    prep_x_kernel<<<3125, 256, 0, stream>>>((const float4*)x, xb);
    hist_kernel<<<6250, 256, 0, stream>>>(ei, cnt);
    bsum_kernel<<<NBS, 256, 0, stream>>>(cnt, bsum);
    bscan_kernel<<<1, 256, 0, stream>>>(bsum, boffs);
    apply_kernel<<<NBS, 256, 0, stream>>>(cnt, boffs, cursor, invdeg);
    scatter_kernel<<<6250, 256, 0, stream>>>(ei, cursor, ea, sed, eab);

    edge_mfma<<<1024, 256, 0, stream>>>(xb, sed, eab, wb1, bf1, bs1, agg);
    resid2_kernel<<<3125, 256, 0, stream>>>((const float4*)agg, invdeg, (const float4*)x, hb);
    hipMemsetAsync(agg, 0, 12800000, stream);
    edge_mfma<<<1024, 256, 0, stream>>>(hb, sed, eab, wb2, bf2, bs2, agg);
    pool2_kernel<<<782, 256, 0, stream>>>(agg, invdeg, hb, batch, gsum, gcnt);
    head_kernel<<<NUM_GRAPHS, 64, 0, stream>>>(gsum, gcnt, w1, b1, w2, b2, out);
}

// Round 17
// 547.728 us; speedup vs baseline: 1.1362x; 1.0892x over previous
//
#include <hip/hip_runtime.h>
#include <hip/hip_bf16.h>

#define N_NODES 50000
#define N_EDGES 1600000
#define IN_CH 64
#define NUM_HID 256
#define NUM_CLASSES 16
#define NUM_GRAPHS 512
#define NBS 196  // ceil(N_NODES/256)

typedef short bf16x8 __attribute__((ext_vector_type(8)));
typedef float f32x4 __attribute__((ext_vector_type(4)));

#if __has_builtin(__builtin_amdgcn_rcpf)
#define RCPF(x) __builtin_amdgcn_rcpf(x)
#else
#define RCPF(x) (1.0f / (x))
#endif

__device__ inline unsigned short f2b(float f) {
    unsigned int u = __float_as_uint(f);
    unsigned int r = (u + 0x7FFF + ((u >> 16) & 1)) >> 16;
    return (unsigned short)r;
}
__device__ inline float b2f(unsigned short u) {
    return __uint_as_float(((unsigned int)u) << 16);
}

// ---------------- preprocessing ----------------
__global__ void prep_w_kernel(const float* __restrict__ wf1, const float* __restrict__ ws1,
                              const float* __restrict__ wf2, const float* __restrict__ ws2,
                              unsigned short* __restrict__ wb1, unsigned short* __restrict__ wb2) {
    int i = blockIdx.x * 256 + threadIdx.x;
    if (i >= 128 * 160) return;
    int r = i / 160, k = i - r * 160;
    wb1[i] = f2b(r < 64 ? wf1[r * 160 + k] : ws1[(r - 64) * 160 + k]);
    wb2[i] = f2b(r < 64 ? wf2[r * 160 + k] : ws2[(r - 64) * 160 + k]);
}

__global__ void prep_x_kernel(const float4* __restrict__ x, unsigned short* __restrict__ xb) {
    int i = blockIdx.x * 256 + threadIdx.x;
    if (i >= N_NODES * 16) return;
    float4 v = x[i];
    ushort4 u; u.x = f2b(v.x); u.y = f2b(v.y); u.z = f2b(v.z); u.w = f2b(v.w);
    *(ushort4*)(xb + i * 4) = u;
}

__global__ void hist_kernel(const int* __restrict__ ei, int* __restrict__ cnt) {
    int i = blockIdx.x * 256 + threadIdx.x;
    if (i < N_EDGES) atomicAdd(&cnt[ei[N_EDGES + i]], 1);
}

__global__ void bsum_kernel(const int* __restrict__ cnt, int* __restrict__ bsum) {
    __shared__ int sm[256];
    int i = blockIdx.x * 256 + threadIdx.x;
    sm[threadIdx.x] = (i < N_NODES) ? cnt[i] : 0;
    __syncthreads();
    for (int off = 128; off > 0; off >>= 1) {
        if (threadIdx.x < off) sm[threadIdx.x] += sm[threadIdx.x + off];
        __syncthreads();
    }
    if (threadIdx.x == 0) bsum[blockIdx.x] = sm[0];
}

__global__ void bscan_kernel(const int* __restrict__ bsum, int* __restrict__ boffs) {
    __shared__ int sm[256];
    int t = threadIdx.x;
    int v = (t < NBS) ? bsum[t] : 0;
    sm[t] = v; __syncthreads();
    for (int off = 1; off < 256; off <<= 1) {
        int u = (t >= off) ? sm[t - off] : 0;
        __syncthreads();
        sm[t] += u;
        __syncthreads();
    }
    if (t < NBS) boffs[t] = sm[t] - v;  // exclusive
}

__global__ void apply_kernel(const int* __restrict__ cnt, const int* __restrict__ boffs,
                             int* __restrict__ cursor, float* __restrict__ invdeg) {
    __shared__ int sm[256];
    int t = threadIdx.x, i = blockIdx.x * 256 + t;
    int c = (i < N_NODES) ? cnt[i] : 0;
    sm[t] = c; __syncthreads();
    for (int off = 1; off < 256; off <<= 1) {
        int u = (t >= off) ? sm[t - off] : 0;
        __syncthreads();
        sm[t] += u;
        __syncthreads();
    }
    if (i < N_NODES) {
        cursor[i] = boffs[blockIdx.x] + sm[t] - c;
        invdeg[i] = 1.0f / fmaxf((float)c, 1.0f);
    }
}

// scatter + in-place sort of edge_attr to dst-order (bf16), fused
__global__ void scatter_kernel(const int* __restrict__ ei, int* __restrict__ cursor,
                               const float* __restrict__ ea,
                               int2* __restrict__ sed, unsigned short* __restrict__ eab) {
    int e = blockIdx.x * 256 + threadIdx.x;
    if (e >= N_EDGES) return;
    int s = ei[e], d = ei[N_EDGES + e];
    int p = atomicAdd(&cursor[d], 1);
    sed[p] = make_int2(s, d);
    const float4* src = (const float4*)(ea + (size_t)e * 32);
    unsigned short* dst = eab + (size_t)p * 32;
    #pragma unroll
    for (int j = 0; j < 8; ++j) {
        float4 v = src[j];
        ushort4 u; u.x = f2b(v.x); u.y = f2b(v.y); u.z = f2b(v.z); u.w = f2b(v.w);
        *(ushort4*)(dst + j * 4) = u;
    }
}

// ---------------- edge pass: WAVE-PRIVATE 16-edge tiles, zero main-loop barriers ----
// B (both matrices) in LDS, fragment-major (read-only after one-time stage).
// Each wave: gather 5 A-frags to regs -> 40 MFMA (B from LDS) -> act in regs ->
// ballot run-reduce -> ONE 64-lane atomic per run. Waves fully independent.
__global__ __launch_bounds__(256, 2)
void edge_mfma(const unsigned short* __restrict__ xb,
               const int2* __restrict__ sed, const unsigned short* __restrict__ eab,
               const unsigned short* __restrict__ wb,
               const float* __restrict__ bfv, const float* __restrict__ bsv,
               float* __restrict__ agg)
{
    // Bl[frag=mat*20+chb*5+ks][lane][8 shorts]: 40*64*16B = 40 KB
    __shared__ __align__(16) unsigned short Bl[40 * 64 * 8];

    const int tid = threadIdx.x;
    const int lane = tid & 63, lr = lane & 15, lq = lane >> 4;

    // one-time B stage (frag-major so hot-loop reads are lane*16B = conflict-free)
    for (int j = tid; j < 40 * 64; j += 256) {
        int f = j >> 6, ls = j & 63;
        int lq2 = ls >> 4, lr2 = ls & 15;
        int mat = f / 20, rem = f - mat * 20, chb = rem / 5, ks = rem - chb * 5;
        bf16x8 v = *(const bf16x8*)(wb + (size_t)(mat * 64 + chb * 16 + lr2) * 160 + ks * 32 + lq2 * 8);
        *(bf16x8*)&Bl[(size_t)j * 8] = v;
    }
    __syncthreads();  // only barrier in the kernel

    float biasF[4], biasS[4];
    #pragma unroll
    for (int chb = 0; chb < 4; ++chb) {
        biasF[chb] = bfv[chb * 16 + lr];
        biasS[chb] = bsv[chb * 16 + lr];
    }

    const int NT16 = N_EDGES / 16;           // 100000 wave-tiles
    const int wg = blockIdx.x * 4 + (tid >> 6);
    const int wstride = gridDim.x * 4;
    const int lq4 = lq * 4;

    for (int T = wg; T < NT16; T += wstride) {
        const int e0 = T * 16;
        int2 sd = sed[e0 + lr];              // dst/src for this lane's edge (lr)
        const int dme = sd.y, sme = sd.x;

        // ---- A-frags direct to registers ----
        bf16x8 ad0 = *(const bf16x8*)(xb + (size_t)dme * 64 + lq * 8);
        bf16x8 ad1 = *(const bf16x8*)(xb + (size_t)dme * 64 + 32 + lq * 8);
        bf16x8 as0 = *(const bf16x8*)(xb + (size_t)sme * 64 + lq * 8);
        bf16x8 as1 = *(const bf16x8*)(xb + (size_t)sme * 64 + 32 + lq * 8);
        bf16x8 ae  = *(const bf16x8*)(eab + (size_t)(e0 + lr) * 32 + lq * 8);

        // ---- 40 MFMA, B from LDS (frag-major, 16B/lane stride) ----
        f32x4 aF[4] = {}; f32x4 aS[4] = {};
        #pragma unroll
        for (int ks = 0; ks < 5; ++ks) {
            bf16x8 a = (ks == 0) ? ad0 : (ks == 1) ? ad1 : (ks == 2) ? as0 : (ks == 3) ? as1 : ae;
            #pragma unroll
            for (int chb = 0; chb < 4; ++chb) {
                bf16x8 b0 = *(const bf16x8*)&Bl[(size_t)((0 * 20 + chb * 5 + ks) * 64 + lane) * 8];
                bf16x8 b1 = *(const bf16x8*)&Bl[(size_t)((1 * 20 + chb * 5 + ks) * 64 + lane) * 8];
                aF[chb] = __builtin_amdgcn_mfma_f32_16x16x32_bf16(a, b0, aF[chb], 0, 0, 0);
                aS[chb] = __builtin_amdgcn_mfma_f32_16x16x32_bf16(a, b1, aS[chb], 0, 0, 0);
            }
        }

        // ---- activation in registers: val[chb][i], edge = lq*4+i, ch = chb*16+lr ----
        float val[16];
        #pragma unroll
        for (int chb = 0; chb < 4; ++chb)
            #pragma unroll
            for (int i = 0; i < 4; ++i) {
                float f = aF[chb][i] + biasF[chb];
                float s = aS[chb][i] + biasS[chb];
                float sig = RCPF(1.0f + __expf(-f));
                float sp = fmaxf(s, 0.0f) + __logf(1.0f + __expf(-fabsf(s)));
                val[chb * 4 + i] = sig * sp;
            }

        // ---- run-reduction over the 16 edges (dst-sorted) ----
        {
            int dprev = __shfl(dme, lane - 1);
            unsigned long long bmask = __ballot((lr == 0) || (dme != dprev)) & 0xFFFFull;
            while (bmask) {
                int lo = (int)__builtin_ctzll(bmask);
                bmask &= bmask - 1;
                int hi = bmask ? (int)__builtin_ctzll(bmask) : 16;
                int dst = __shfl(dme, lo);     // wave-uniform
                float tc[4];
                #pragma unroll
                for (int chb = 0; chb < 4; ++chb) {
                    float s = 0.0f;
                    #pragma unroll
                    for (int i = 0; i < 4; ++i) {
                        int r = lq4 + i;
                        s += ((r >= lo) && (r < hi)) ? val[chb * 4 + i] : 0.0f;
                    }
                    s += __shfl_xor(s, 16);
                    s += __shfl_xor(s, 32);    // butterfly: sum lands in ALL lanes
                    tc[chb] = s;
                }
                float tsel = (lq == 0) ? tc[0] : (lq == 1) ? tc[1] : (lq == 2) ? tc[2] : tc[3];
                atomicAdd(&agg[(size_t)dst * 64 + lq * 16 + lr], tsel);  // one 64-lane atomic/run
            }
        }
    }
}

// ---------------- residual: hb = bf16(agg*inv_deg + x) ----------------
__global__ void resid2_kernel(const float4* __restrict__ agg, const float* __restrict__ inv_deg,
                              const float4* __restrict__ x, unsigned short* __restrict__ hb)
{
    int i = blockIdx.x * 256 + threadIdx.x;
    if (i >= N_NODES * 16) return;
    int n = i >> 4;
    float iv = inv_deg[n];
    float4 a = agg[i], xv = x[i];
    ushort4 u;
    u.x = f2b(a.x * iv + xv.x); u.y = f2b(a.y * iv + xv.y);
    u.z = f2b(a.z * iv + xv.z); u.w = f2b(a.w * iv + xv.w);
    *(ushort4*)(hb + i * 4) = u;
}

// ---------------- layer-2 residual + pooling: run-reduction over SORTED batch ----------------
__global__ void pool2_kernel(const float* __restrict__ agg, const float* __restrict__ inv_deg,
                             const unsigned short* __restrict__ hb, const int* __restrict__ batch,
                             float* __restrict__ gsum, float* __restrict__ gcnt)
{
    const int ch = threadIdx.x & 63, sub = threadIdx.x >> 6;
    const int base = blockIdx.x * 64 + sub * 16;
    float acc = 0.0f;
    int gcur = -1, rl = 0;
    #pragma unroll
    for (int j = 0; j < 16; ++j) {
        int n = base + j;
        if (n >= N_NODES) break;
        int g = batch[n];
        float v = agg[(size_t)n * 64 + ch] * inv_deg[n] + b2f(hb[(size_t)n * 64 + ch]);
        if (g != gcur) {
            if (gcur >= 0) {
                atomicAdd(&gsum[gcur * 64 + ch], acc);
                if (ch == 0) atomicAdd(&gcnt[gcur], (float)rl);
            }
            gcur = g; acc = v; rl = 1;
        } else {
            acc += v; rl++;
        }
    }
    if (gcur >= 0) {
        atomicAdd(&gsum[gcur * 64 + ch], acc);
        if (ch == 0) atomicAdd(&gcnt[gcur], (float)rl);
    }
}

// ---------------- head: MLP + log_softmax ----------------
__global__ __launch_bounds__(64)
void head_kernel(const float* __restrict__ gsum, const float* __restrict__ gcnt,
                 const float* __restrict__ w1, const float* __restrict__ b1,
                 const float* __restrict__ w2, const float* __restrict__ b2,
                 float* __restrict__ out)
{
    __shared__ float gv[64];
    __shared__ float hid[256];
    __shared__ float outv[16];
    const int g = blockIdx.x, t = threadIdx.x;
    float cnt = fmaxf(gcnt[g], 1.0f);
    gv[t] = gsum[g * 64 + t] / cnt;
    __syncthreads();
    #pragma unroll
    for (int r = 0; r < 4; ++r) {
        int c = t + r * 64;
        float acc = b1[c];
        const float4* wr = (const float4*)(w1 + c * 64);
        const float4* gvv = (const float4*)gv;
        #pragma unroll
        for (int k = 0; k < 16; ++k) {
            float4 wv = wr[k], xv = gvv[k];
            acc += wv.x * xv.x + wv.y * xv.y + wv.z * xv.z + wv.w * xv.w;
        }
        hid[c] = fmaxf(acc, 0.0f);
    }
    __syncthreads();
    if (t < 16) {
        float acc = b2[t];
        const float4* wr = (const float4*)(w2 + t * 256);
        const float4* hv = (const float4*)hid;
        for (int k = 0; k < 64; ++k) {
            float4 wv = wr[k], xv = hv[k];
            acc += wv.x * xv.x + wv.y * xv.y + wv.z * xv.z + wv.w * xv.w;
        }
        outv[t] = acc;
    }
    __syncthreads();
    if (t < 16) {
        float m = outv[0];
        #pragma unroll
        for (int j = 1; j < 16; ++j) m = fmaxf(m, outv[j]);
        float ssum = 0.0f;
        #pragma unroll
        for (int j = 0; j < 16; ++j) ssum += expf(outv[j] - m);
        out[g * 16 + t] = outv[t] - m - logf(ssum);
    }
}

extern "C" void kernel_launch(void* const* d_in, const int* in_sizes, int n_in,
                              void* d_out, int out_size, void* d_ws, size_t ws_size,
                              hipStream_t stream)
{
    const float* x     = (const float*)d_in[0];
    const int*   ei    = (const int*)d_in[1];
    const float* ea    = (const float*)d_in[2];
    const int*   batch = (const int*)d_in[3];
    const float* wf1 = (const float*)d_in[4];
    const float* bf1 = (const float*)d_in[5];
    const float* ws1 = (const float*)d_in[6];
    const float* bs1 = (const float*)d_in[7];
    const float* wf2 = (const float*)d_in[8];
    const float* bf2 = (const float*)d_in[9];
    const float* ws2 = (const float*)d_in[10];
    const float* bs2 = (const float*)d_in[11];
    const float* w1 = (const float*)d_in[12];
    const float* b1 = (const float*)d_in[13];
    const float* w2 = (const float*)d_in[14];
    const float* b2 = (const float*)d_in[15];
    float* out = (float*)d_out;

    char* ws = (char*)d_ws;
    int*   cnt    = (int*)(ws + 0x0000000);           // 200 KB
    int*   cursor = (int*)(ws + 0x0040000);           // 200 KB
    float* invdeg = (float*)(ws + 0x0080000);         // 200 KB
    int*   bsum   = (int*)(ws + 0x00C0000);           // 1 KB
    int*   boffs  = (int*)(ws + 0x00C1000);           // 1 KB
    int2*  sed    = (int2*)(ws + 0x0100000);          // 12.8 MB
    unsigned short* xb  = (unsigned short*)(ws + 0x1500000);  // 6.4 MB
    unsigned short* hb  = (unsigned short*)(ws + 0x1C00000);  // 6.4 MB
    float* agg = (float*)(ws + 0x2300000);            // 12.8 MB
    unsigned short* wb1 = (unsigned short*)(ws + 0x3000000);  // 40 KB
    unsigned short* wb2 = (unsigned short*)(ws + 0x3010000);  // 40 KB
    float* gsum = (float*)(ws + 0x3020000);           // 128 KB
    float* gcnt = (float*)(ws + 0x3040000);           // 2 KB
    unsigned short* eab = (unsigned short*)(ws + 0x3100000);  // 102.4 MB (fits: r8-r15 ran this)

    hipMemsetAsync(cnt, 0, 200000, stream);
    hipMemsetAsync(agg, 0, 12800000, stream);
    hipMemsetAsync(gsum, 0, 131072 + 2048, stream);

    prep_w_kernel<<<80, 256, 0, stream>>>(wf1, ws1, wf2, ws2, wb1, wb2);
    prep_x_kernel<<<3125, 256, 0, stream>>>((const float4*)x, xb);
    hist_kernel<<<6250, 256, 0, stream>>>(ei, cnt);
    bsum_kernel<<<NBS, 256, 0, stream>>>(cnt, bsum);
    bscan_kernel<<<1, 256, 0, stream>>>(bsum, boffs);
    apply_kernel<<<NBS, 256, 0, stream>>>(cnt, boffs, cursor, invdeg);
    scatter_kernel<<<6250, 256, 0, stream>>>(ei, cursor, ea, sed, eab);

    edge_mfma<<<1024, 256, 0, stream>>>(xb, sed, eab, wb1, bf1, bs1, agg);
    resid2_kernel<<<3125, 256, 0, stream>>>((const float4*)agg, invdeg, (const float4*)x, hb);
    hipMemsetAsync(agg, 0, 12800000, stream);
    edge_mfma<<<1024, 256, 0, stream>>>(hb, sed, eab, wb2, bf2, bs2, agg);
    pool2_kernel<<<782, 256, 0, stream>>>(agg, invdeg, hb, batch, gsum, gcnt);
    head_kernel<<<NUM_GRAPHS, 64, 0, stream>>>(gsum, gcnt, w1, b1, w2, b2, out);
}